// Round 7
// baseline (683.706 us; speedup 1.0000x reference)
//
#include <hip/hip_runtime.h>

typedef float  f32x4 __attribute__((ext_vector_type(4)));
typedef short  s16x8 __attribute__((ext_vector_type(8)));
typedef short  s16x4 __attribute__((ext_vector_type(4)));
typedef int    i32x4 __attribute__((ext_vector_type(4)));

#define MFMA16(a,b,c) __builtin_amdgcn_mfma_f32_16x16x32_bf16(a,b,c,0,0,0)

static __device__ __forceinline__ f32x4 mfma_pv(s16x4 a, s16x4 b, f32x4 c){
#if defined(__HIP_DEVICE_COMPILE__)
    return __builtin_amdgcn_mfma_f32_16x16x16bf16_1k(a, b, c, 0, 0, 0);
#else
    (void)a; (void)b; return c;
#endif
}

// B=4, N1=N2=4096, D=H=256. Inputs fp32, output fp32.
static __device__ __forceinline__ unsigned short f2bf(float f){
    union { float f; unsigned int u; } x; x.f = f;
    unsigned int r = x.u + 0x7fffu + ((x.u >> 16) & 1u);   // RNE
    return (unsigned short)(r >> 16);
}

// ---------------- kernel 1: W^T -> bf16, MFMA B-frag order ----------------
__global__ void wt_prep(const float* __restrict__ Wq, const float* __restrict__ Wk,
                        const float* __restrict__ Wv, unsigned short* __restrict__ wt){
    const int p = blockIdx.y;
    const int o8 = blockIdx.x*256 + threadIdx.x;       // [0, 8192)
    const float* W = (p==0) ? Wq : ((p==1) ? Wk : Wv);
    const int lane = o8 & 63, t = (o8 >> 6) & 15, ks = o8 >> 10;
    const int quad = lane >> 4, lq = lane & 15;
    s16x8 o;
    #pragma unroll
    for(int j=0;j<8;j++)
        o[j] = (short)f2bf(W[(ks*32 + quad*8 + j)*256 + 16*t + lq]);
    *(s16x8*)(wt + (size_t)p*65536 + (size_t)o8*8) = o;
}

// -------- staging helper: x tile (64x256 fp32) -> bf16 LDS (stride 264) ------
static __device__ __forceinline__ void stage_x(const float* x, size_t row0,
                                               int tid, unsigned short* sX){
    const float* xg = x + row0*256;
    #pragma unroll
    for(int rr=0; rr<16; rr++){
        int c = tid + rr*256;
        int row = c>>6, cc = c&63;
        float4 f = *(const float4*)(xg + row*256 + cc*4);
        unsigned short* d = &sX[row*264 + cc*4];
        d[0]=f2bf(f.x); d[1]=f2bf(f.y); d[2]=f2bf(f.z); d[3]=f2bf(f.w);
    }
}

// ---------------- kernel 2: projections + mask bit-pack, one launch ----------
// p=0: Q row-major. p=1: K -> kfrag. p=2: V -> vfrag. p=3: mask -> bitmask.
// Mask pack (p=3): 268MB int32 -> 8.4MB bits so attn's working set (K/V 64MB
// + Q 32MB + bits 8MB) fits the 256MB L3 -- the raw mask stream was evicting
// K/V every dispatch (R5 post-mortem: K/V loads ran at HBM latency).
// Packed layout: pm[row][kt] = uint64; bit(c*16 + j) = (mask[row][kt*64+4j+c]>0)
// so the attn-side extract is one shift by (4w+quad) then bits {0,16,32,48}.
// Pack reads are nontemporal: one-time stream must not evict the frags that
// the sibling p=0..2 blocks are writing.
__global__ __launch_bounds__(256) void proj_all(const float* __restrict__ x1,
        const float* __restrict__ x2, const unsigned short* __restrict__ wt,
        const float* __restrict__ bq, const float* __restrict__ bk,
        const float* __restrict__ bv, int b0,
        unsigned short* __restrict__ qdst, unsigned short* __restrict__ kfrag,
        unsigned short* __restrict__ vfrag,
        const int* __restrict__ mask, unsigned long long* __restrict__ pm){
    const int rt = blockIdx.x, p = blockIdx.y, z = blockIdx.z;
    const int zz = b0 + z;
    const int tid = threadIdx.x, w = tid>>6, lane = tid&63, quad = lane>>4, lq = lane&15;

    if(p == 3){          // ---- mask bit-pack: 64 rows per block ----
        #pragma unroll 1
        for(int rr=0; rr<16; rr++){
            const size_t lrow = (size_t)rt*64 + w*16 + rr;
            const int* mrow = mask + ((size_t)zz*4096 + lrow)*4096;
            unsigned long long* prow = pm +
                ((gridDim.z==4) ? ((size_t)zz*4096 + lrow) : lrow)*64;
            #pragma unroll 1
            for(int g=0; g<16; g++){
                const i32x4* pv = (const i32x4*)(mrow + g*256 + lane*4);
#if __has_builtin(__builtin_nontemporal_load)
                i32x4 v = __builtin_nontemporal_load(pv);
#else
                i32x4 v = *pv;
#endif
                unsigned long long b0_ = __ballot(v.x > 0);
                unsigned long long b1_ = __ballot(v.y > 0);
                unsigned long long b2_ = __ballot(v.z > 0);
                unsigned long long b3_ = __ballot(v.w > 0);
                if(lane < 4){
                    unsigned long long wd =  ((b0_>>(16*lane))&0xFFFFull)
                        | (((b1_>>(16*lane))&0xFFFFull)<<16)
                        | (((b2_>>(16*lane))&0xFFFFull)<<32)
                        | (((b3_>>(16*lane))&0xFFFFull)<<48);
                    prow[g*4 + lane] = wd;
                }
            }
        }
        return;
    }

    __shared__ __align__(16) unsigned short sX[64*264];
    const float* x = (p==0) ? x1 : x2;
    stage_x(x, (size_t)(zz*64 + rt)*64, tid, sX);
    __syncthreads();

    s16x8 a[8];
    #pragma unroll
    for(int ks=0; ks<8; ks++)
        a[ks] = *(const s16x8*)(&sX[(16*w+lq)*264 + ks*32 + quad*8]);

    f32x4 acc[16];
    #pragma unroll
    for(int t=0;t<16;t++) acc[t] = (f32x4)(0.0f);
    const unsigned short* wtp = wt + (size_t)p*65536;
    #pragma unroll
    for(int ks=0; ks<8; ks++){
        #pragma unroll
        for(int t=0; t<16; t++){
            s16x8 bf_ = *(const s16x8*)(wtp + (((size_t)(ks*16 + t)*64 + lane)*8));
            acc[t] = MFMA16(a[ks], bf_, acc[t]);
        }
    }

    if(p == 0){          // Q row-major
        #pragma unroll
        for(int t=0;t<16;t++){
            float bvf = bq[16*t+lq];
            #pragma unroll
            for(int r=0;r<4;r++){
                size_t row = (size_t)(zz*64 + rt)*64 + 16*w + 4*quad + r;
                qdst[row*256 + 16*t + lq] = f2bf(acc[t][r] + bvf);
            }
        }
    } else if(p == 1){   // K -> kfrag via LDS round-trip
        __syncthreads();
        #pragma unroll
        for(int t=0;t<16;t++){
            float bvf = bk[16*t+lq];
            #pragma unroll
            for(int r=0;r<4;r++)
                sX[(16*w + 4*quad + r)*264 + 16*t + lq] = f2bf(acc[t][r] + bvf);
        }
        __syncthreads();
        unsigned short* kd = kfrag + (size_t)z*1048576;
        #pragma unroll
        for(int ks=0; ks<8; ks++){
            s16x8 v = *(const s16x8*)(&sX[(16*w + lq)*264 + 32*ks + 8*quad]);
            *(s16x8*)(kd + ((((size_t)rt*4 + w)*8 + ks)*64 + lane)*8) = v;
        }
    } else {             // V -> vfrag direct
        unsigned short* vd = vfrag + (size_t)z*1048576;
        #pragma unroll
        for(int t2=0; t2<8; t2++){
            float b0f = bv[16*(2*t2  )+lq];
            float b1f = bv[16*(2*t2+1)+lq];
            s16x8 o;
            #pragma unroll
            for(int r=0;r<4;r++){
                o[r]   = (short)f2bf(acc[2*t2  ][r] + b0f);
                o[4+r] = (short)f2bf(acc[2*t2+1][r] + b1f);
            }
            *(s16x8*)(vd + ((((size_t)rt*4 + w)*8 + t2)*64 + lane)*8) = o;
        }
    }
}

// ------- kernel 3: flash attn, reg-streaming + in-block KV-split -------------
// Block = 32 q-rows, 512 threads = 8 waves: half = wave>>2 (kt-range half),
// w = wave&3 (n2-slice). Grid = 512. Register note (R5 post-mortem): this
// per-wave tile needs ~128 arch-VGPR + 128 AGPR (oacc) = 256 total on the
// unified gfx950 file -> 2 waves/SIMD is the hard ceiling; launch_bounds
// (512,2) keeps arch-VGPR at 128 with zero spill. Perf therefore depends on
// load LATENCY, which this round attacks by making K/V L3-resident (mask is
// now read as 8B/tile bitmask instead of the 268MB int stream that was
// thrashing L3). Mask bits: pm[row][kt]>> (4w+quad), bits {0,16,32,48} are
// r=0..3 (see pack comment). No LDS/barriers in the main loop.
__global__ __launch_bounds__(512,2) void attn(
        const unsigned short* __restrict__ qb, const unsigned short* __restrict__ kfrag,
        const unsigned short* __restrict__ vfrag,
        const unsigned long long* __restrict__ pmask,
        float* __restrict__ out, int b0){
    const int bid = blockIdx.x;
    int b, qt, bk_;
    if(gridDim.x == 512){ b = (bid&7)>>1; qt = (bid>>3)*2 + (bid&1); bk_ = b; }
    else                { b = b0; qt = bid; bk_ = 0; }
    const int tid = threadIdx.x, w4 = tid>>6, lane = tid&63, quad = lane>>4, lq = lane&15;
    const int half = w4>>2, w = w4&3;
    const int qbase = qt*32;
    const int kt0 = half*32;
    const size_t rowb = (gridDim.x == 512) ? (size_t)b*4096 : 0;

    __shared__ __align__(16) unsigned char smem[67648];  // epilogue scratch only

    // Q as B-operand frags (rows qbase+16rg+lq)
    s16x8 qf[2][8];
    #pragma unroll
    for(int rg=0; rg<2; rg++){
        size_t row = (size_t)(b*4096 + qbase + 16*rg + lq);
        #pragma unroll
        for(int ks=0; ks<8; ks++)
            qf[rg][ks] = *(const s16x8*)(qb + row*256 + ks*32 + quad*8);
    }

    f32x4 oacc[16][2];                 // O^T partial: h=16t+4quad+r, q=16rg+lq
    #pragma unroll
    for(int t=0;t<16;t++){ oacc[t][0] = (f32x4)(0.0f); oacc[t][1] = (f32x4)(0.0f); }
    float rsum[2] = {0.0f, 0.0f};

    const unsigned char* kfb = (const unsigned char*)(kfrag + (size_t)bk_*1048576);
    const unsigned char* vfb = (const unsigned char*)(vfrag + (size_t)bk_*1048576);
    const unsigned long long* pm0 = pmask + ((size_t)(rowb + qbase) + lq)*64;
    const unsigned long long* pm1 = pm0 + 16*64;
    const int sh = 4*w + quad;

    // prologue: packed mask for this half's first tile (pre-shifted by sh)
    unsigned long long mM0 = pm0[kt0] >> sh;
    unsigned long long mM1 = pm1[kt0] >> sh;

    for(int kt=kt0; kt<kt0+32; kt++){
        const unsigned char* gK = kfb + (size_t)kt*32768;
        const unsigned char* gV = vfb + (size_t)kt*32768;

        // ---- S^T: D[n2local=4quad+r][q=lq], K frags 4-at-a-time from global --
        f32x4 sacc0 = (f32x4)(0.0f), sacc1 = (f32x4)(0.0f);
        {
            s16x8 kf_[4];
            #pragma unroll
            for(int ks=0; ks<4; ks++)
                kf_[ks] = *(const s16x8*)(gK + (((unsigned)(w*8 + ks)*64 + lane)*16));
            #pragma unroll
            for(int ks=0; ks<4; ks++){
                sacc0 = MFMA16(kf_[ks], qf[0][ks], sacc0);
                sacc1 = MFMA16(kf_[ks], qf[1][ks], sacc1);
            }
            #pragma unroll
            for(int ks=0; ks<4; ks++)
                kf_[ks] = *(const s16x8*)(gK + (((unsigned)(w*8 + 4 + ks)*64 + lane)*16));
            #pragma unroll
            for(int ks=0; ks<4; ks++){
                sacc0 = MFMA16(kf_[ks], qf[0][4+ks], sacc0);
                sacc1 = MFMA16(kf_[ks], qf[1][4+ks], sacc1);
            }
        }

        // ---- mask bits + exp + pack (C rows 4quad+r == PV k=4quad+j) ----
        s16x4 pb0, pb1;
        {
            float p;
            p = (mM0     &1)? __expf(sacc0[0]*0.0625f):1.0f; rsum[0]+=p; pb0[0]=(short)f2bf(p);
            p = ((mM0>>16)&1)? __expf(sacc0[1]*0.0625f):1.0f; rsum[0]+=p; pb0[1]=(short)f2bf(p);
            p = ((mM0>>32)&1)? __expf(sacc0[2]*0.0625f):1.0f; rsum[0]+=p; pb0[2]=(short)f2bf(p);
            p = ((mM0>>48)&1)? __expf(sacc0[3]*0.0625f):1.0f; rsum[0]+=p; pb0[3]=(short)f2bf(p);
            p = (mM1     &1)? __expf(sacc1[0]*0.0625f):1.0f; rsum[1]+=p; pb1[0]=(short)f2bf(p);
            p = ((mM1>>16)&1)? __expf(sacc1[1]*0.0625f):1.0f; rsum[1]+=p; pb1[1]=(short)f2bf(p);
            p = ((mM1>>32)&1)? __expf(sacc1[2]*0.0625f):1.0f; rsum[1]+=p; pb1[2]=(short)f2bf(p);
            p = ((mM1>>48)&1)? __expf(sacc1[3]*0.0625f):1.0f; rsum[1]+=p; pb1[3]=(short)f2bf(p);
        }

        // ---- mask prefetch kt+1 (full body of slack; last iter harmless) ----
        if(kt < 63){
            mM0 = pm0[kt+1] >> sh;
            mM1 = pm1[kt+1] >> sh;
        }

        // ---- PV: V frags 4-at-a-time from global ----
        {
            s16x8 vf_[4];
            #pragma unroll
            for(int t2=0; t2<4; t2++)
                vf_[t2] = *(const s16x8*)(gV + (((unsigned)(w*8 + t2)*64 + lane)*16));
            #pragma unroll
            for(int t2=0; t2<4; t2++){
                s16x4 vlo = __builtin_shufflevector(vf_[t2], vf_[t2], 0,1,2,3);
                s16x4 vhi = __builtin_shufflevector(vf_[t2], vf_[t2], 4,5,6,7);
                oacc[2*t2  ][0] = mfma_pv(vlo, pb0, oacc[2*t2  ][0]);
                oacc[2*t2  ][1] = mfma_pv(vlo, pb1, oacc[2*t2  ][1]);
                oacc[2*t2+1][0] = mfma_pv(vhi, pb0, oacc[2*t2+1][0]);
                oacc[2*t2+1][1] = mfma_pv(vhi, pb1, oacc[2*t2+1][1]);
            }
            #pragma unroll
            for(int t2=0; t2<4; t2++)
                vf_[t2] = *(const s16x8*)(gV + (((unsigned)(w*8 + 4 + t2)*64 + lane)*16));
            #pragma unroll
            for(int t2=0; t2<4; t2++){
                s16x4 vlo = __builtin_shufflevector(vf_[t2], vf_[t2], 0,1,2,3);
                s16x4 vhi = __builtin_shufflevector(vf_[t2], vf_[t2], 4,5,6,7);
                oacc[2*(4+t2)  ][0] = mfma_pv(vlo, pb0, oacc[2*(4+t2)  ][0]);
                oacc[2*(4+t2)  ][1] = mfma_pv(vlo, pb1, oacc[2*(4+t2)  ][1]);
                oacc[2*(4+t2)+1][0] = mfma_pv(vhi, pb0, oacc[2*(4+t2)+1][0]);
                oacc[2*(4+t2)+1][1] = mfma_pv(vhi, pb1, oacc[2*(4+t2)+1][1]);
            }
        }
    }

    // ---- epilogue: 8-way reduction (4 n2-slices x 2 kt-halves) --------------
    // sRS [8][32] @0 (1KB); sRed [8][2081] @1024 (66.6KB).
    float* sRS  = (float*)smem;
    float* sRed = (float*)(smem + 1024);
    #pragma unroll
    for(int rg=0; rg<2; rg++){
        float v = rsum[rg];
        v += __shfl_xor(v, 16);
        v += __shfl_xor(v, 32);
        if(quad == 0) sRS[w4*32 + 16*rg + lq] = v;
    }
    for(int c=0; c<4; c++){
        __syncthreads();
        #pragma unroll
        for(int tt=0; tt<4; tt++){
            int t = 4*c + tt;
            #pragma unroll
            for(int rg=0; rg<2; rg++){
                #pragma unroll
                for(int r=0; r<4; r++)
                    sRed[w4*2081 + (16*rg+lq)*65 + 16*tt + 4*quad + r] = oacc[t][rg][r];
            }
        }
        __syncthreads();
        #pragma unroll
        for(int j=0; j<4; j++){
            int idx = j*512 + tid;              // 2048 = 32q x 64h elements
            int hl = idx & 63, q = idx >> 6;
            float s  = sRed[0*2081 + q*65+hl] + sRed[1*2081 + q*65+hl]
                     + sRed[2*2081 + q*65+hl] + sRed[3*2081 + q*65+hl]
                     + sRed[4*2081 + q*65+hl] + sRed[5*2081 + q*65+hl]
                     + sRed[6*2081 + q*65+hl] + sRed[7*2081 + q*65+hl];
            float rs = sRS[0*32+q] + sRS[1*32+q] + sRS[2*32+q] + sRS[3*32+q]
                     + sRS[4*32+q] + sRS[5*32+q] + sRS[6*32+q] + sRS[7*32+q];
            out[((size_t)(b*4096 + qbase + q))*256 + 64*c + hl] = s / rs;
        }
    }
}

extern "C" void kernel_launch(void* const* d_in, const int* in_sizes, int n_in,
                              void* d_out, int out_size, void* d_ws, size_t ws_size,
                              hipStream_t stream){
    (void)in_sizes; (void)n_in; (void)out_size;
    const float* x1 = (const float*)d_in[0];
    const float* x2 = (const float*)d_in[1];
    const int*   mk = (const int*)  d_in[2];
    const float* Wq = (const float*)d_in[3];
    const float* bq = (const float*)d_in[4];
    const float* Wk = (const float*)d_in[5];
    const float* bk = (const float*)d_in[6];
    const float* Wv = (const float*)d_in[7];
    const float* bv = (const float*)d_in[8];
    float* out = (float*)d_out;
    char* ws = (char*)d_ws;

    // ws layout: wt 384K @0 | q 8M | kfrag | vfrag | pmask
    unsigned short* wt = (unsigned short*)ws;
    unsigned short* qb = (unsigned short*)(ws + 393216);
    const size_t kvoff = 393216 + 8388608;

    wt_prep<<<dim3(32,3), 256, 0, stream>>>(Wq, Wk, Wv, wt);

    if(ws_size >= kvoff + 25165824ull){
        unsigned short* kf = (unsigned short*)(ws + kvoff);
        unsigned short* vf = (unsigned short*)(ws + kvoff + 8388608);
        unsigned long long* pmb = (unsigned long long*)(ws + kvoff + 16777216);
        proj_all<<<dim3(64,4,4), 256, 0, stream>>>(x1, x2, wt, bq, bk, bv, 0,
                                                   qb, kf, vf, mk, pmb);
        attn<<<512, 512, 0, stream>>>(qb, kf, vf, pmb, out, 0);
    } else {
        unsigned short* kf = (unsigned short*)(ws + kvoff);
        unsigned short* vf = (unsigned short*)(ws + kvoff + 2097152);
        unsigned long long* pmb = (unsigned long long*)(ws + kvoff + 4194304);
        for(int b=0;b<4;b++){
            proj_all<<<dim3(64,4,1), 256, 0, stream>>>(x1, x2, wt, bq, bk, bv, b,
                                                       qb, kf, vf, mk, pmb);
            attn<<<128, 512, 0, stream>>>(qb, kf, vf, pmb, out, b);
        }
    }
}

// Round 8
// 497.544 us; speedup vs baseline: 1.3742x; 1.3742x over previous
//
#include <hip/hip_runtime.h>

typedef float  f32x4 __attribute__((ext_vector_type(4)));
typedef short  s16x8 __attribute__((ext_vector_type(8)));
typedef short  s16x4 __attribute__((ext_vector_type(4)));
typedef int    i32x4 __attribute__((ext_vector_type(4)));

#define MFMA16(a,b,c) __builtin_amdgcn_mfma_f32_16x16x32_bf16(a,b,c,0,0,0)

static __device__ __forceinline__ f32x4 mfma_pv(s16x4 a, s16x4 b, f32x4 c){
#if defined(__HIP_DEVICE_COMPILE__)
    return __builtin_amdgcn_mfma_f32_16x16x16bf16_1k(a, b, c, 0, 0, 0);
#else
    (void)a; (void)b; return c;
#endif
}

// async global->LDS, 16B per lane: data lands at lds_base(wave-uniform)+lane*16
static __device__ __forceinline__ void glds16(const void* g, void* l){
#if defined(__HIP_DEVICE_COMPILE__)
    __builtin_amdgcn_global_load_lds(
        (const __attribute__((address_space(1))) unsigned int*)g,
        (__attribute__((address_space(3))) unsigned int*)l, 16, 0, 0);
#else
    (void)g; (void)l;
#endif
}

// nontemporal int4 load: one-pass streams (mask) must NOT allocate in L2/L3 --
// the 268MB raw mask ~= L3 size and was evicting the K/V panels (R7 proof:
// removing the stream cut attn FETCH 170->41MB).
static __device__ __forceinline__ i32x4 ntload4(const int* p){
#if __has_builtin(__builtin_nontemporal_load)
    return __builtin_nontemporal_load((const i32x4*)p);
#else
    return *(const i32x4*)p;
#endif
}
static __device__ __forceinline__ void ntstoref(float v, float* p){
#if __has_builtin(__builtin_nontemporal_store)
    __builtin_nontemporal_store(v, p);
#else
    *p = v;
#endif
}

// B=4, N1=N2=4096, D=H=256. Inputs fp32, output fp32.
static __device__ __forceinline__ unsigned short f2bf(float f){
    union { float f; unsigned int u; } x; x.f = f;
    unsigned int r = x.u + 0x7fffu + ((x.u >> 16) & 1u);   // RNE
    return (unsigned short)(r >> 16);
}

// ---------------- kernel 1: W^T -> bf16, MFMA B-frag order ----------------
__global__ void wt_prep(const float* __restrict__ Wq, const float* __restrict__ Wk,
                        const float* __restrict__ Wv, unsigned short* __restrict__ wt){
    const int p = blockIdx.y;
    const int o8 = blockIdx.x*256 + threadIdx.x;       // [0, 8192)
    const float* W = (p==0) ? Wq : ((p==1) ? Wk : Wv);
    const int lane = o8 & 63, t = (o8 >> 6) & 15, ks = o8 >> 10;
    const int quad = lane >> 4, lq = lane & 15;
    s16x8 o;
    #pragma unroll
    for(int j=0;j<8;j++)
        o[j] = (short)f2bf(W[(ks*32 + quad*8 + j)*256 + 16*t + lq]);
    *(s16x8*)(wt + (size_t)p*65536 + (size_t)o8*8) = o;
}

// -------- staging helper: x tile (64x256 fp32) -> bf16 LDS (stride 264) ------
static __device__ __forceinline__ void stage_x(const float* x, size_t row0,
                                               int tid, unsigned short* sX){
    const float* xg = x + row0*256;
    #pragma unroll
    for(int rr=0; rr<16; rr++){
        int c = tid + rr*256;
        int row = c>>6, cc = c&63;
        float4 f = *(const float4*)(xg + row*256 + cc*4);
        unsigned short* d = &sX[row*264 + cc*4];
        d[0]=f2bf(f.x); d[1]=f2bf(f.y); d[2]=f2bf(f.z); d[3]=f2bf(f.w);
    }
}

// ---------------- kernel 2: ALL projections, one launch ----------------------
__global__ __launch_bounds__(256) void proj_all(const float* __restrict__ x1,
        const float* __restrict__ x2, const unsigned short* __restrict__ wt,
        const float* __restrict__ bq, const float* __restrict__ bk,
        const float* __restrict__ bv, int b0,
        unsigned short* __restrict__ qdst, unsigned short* __restrict__ kfrag,
        unsigned short* __restrict__ vfrag){
    const int rt = blockIdx.x, p = blockIdx.y, z = blockIdx.z;
    const int zz = b0 + z;
    const int tid = threadIdx.x, w = tid>>6, lane = tid&63, quad = lane>>4, lq = lane&15;
    __shared__ __align__(16) unsigned short sX[64*264];

    const float* x = (p==0) ? x1 : x2;
    stage_x(x, (size_t)(zz*64 + rt)*64, tid, sX);
    __syncthreads();

    s16x8 a[8];
    #pragma unroll
    for(int ks=0; ks<8; ks++)
        a[ks] = *(const s16x8*)(&sX[(16*w+lq)*264 + ks*32 + quad*8]);

    f32x4 acc[16];
    #pragma unroll
    for(int t=0;t<16;t++) acc[t] = (f32x4)(0.0f);
    const unsigned short* wtp = wt + (size_t)p*65536;
    #pragma unroll
    for(int ks=0; ks<8; ks++){
        #pragma unroll
        for(int t=0; t<16; t++){
            s16x8 bf_ = *(const s16x8*)(wtp + (((size_t)(ks*16 + t)*64 + lane)*8));
            acc[t] = MFMA16(a[ks], bf_, acc[t]);
        }
    }

    if(p == 0){          // Q row-major
        #pragma unroll
        for(int t=0;t<16;t++){
            float bvf = bq[16*t+lq];
            #pragma unroll
            for(int r=0;r<4;r++){
                size_t row = (size_t)(zz*64 + rt)*64 + 16*w + 4*quad + r;
                qdst[row*256 + 16*t + lq] = f2bf(acc[t][r] + bvf);
            }
        }
    } else if(p == 1){   // K -> kfrag via LDS round-trip
        __syncthreads();
        #pragma unroll
        for(int t=0;t<16;t++){
            float bvf = bk[16*t+lq];
            #pragma unroll
            for(int r=0;r<4;r++)
                sX[(16*w + 4*quad + r)*264 + 16*t + lq] = f2bf(acc[t][r] + bvf);
        }
        __syncthreads();
        unsigned short* kd = kfrag + (size_t)z*1048576;
        #pragma unroll
        for(int ks=0; ks<8; ks++){
            s16x8 v = *(const s16x8*)(&sX[(16*w + lq)*264 + 32*ks + 8*quad]);
            *(s16x8*)(kd + ((((size_t)rt*4 + w)*8 + ks)*64 + lane)*8) = v;
        }
    } else {             // V -> vfrag direct
        unsigned short* vd = vfrag + (size_t)z*1048576;
        #pragma unroll
        for(int t2=0; t2<8; t2++){
            float b0f = bv[16*(2*t2  )+lq];
            float b1f = bv[16*(2*t2+1)+lq];
            s16x8 o;
            #pragma unroll
            for(int r=0;r<4;r++){
                o[r]   = (short)f2bf(acc[2*t2  ][r] + b0f);
                o[4+r] = (short)f2bf(acc[2*t2+1][r] + b1f);
            }
            *(s16x8*)(vd + ((((size_t)rt*4 + w)*8 + t2)*64 + lane)*8) = o;
        }
    }
}

// ---------------- kernel 3: flash attn, async-LDS double-buffered ------------
// R1 structure verbatim (best measured attn: 169.9us): 512 thr = 8 waves,
// TM=64 q-rows/block, 2 x 64KB LDS buffers (K 32KB + V 32KB, frag order).
// At top of body kt, right after the barrier, issue the mask prefetch (kt+1,
// reg dbuf) and the async stage of kt+1 into buf[cb^1]; both have the full
// body in flight before the next barrier's vmcnt(0) drain.
// R8 change: mask loads are NONTEMPORAL. R1's drain ran at HBM speed because
// the 268MB mask stream (~= L3 size) evicted the K/V panels from L2/L3;
// nt keeps K/V resident so the staging drain is an L2-rate ~1.2K-cyc wait.
// Output stores are also nontemporal (16MB, written once).
__global__ __launch_bounds__(512,2) void attn(
        const unsigned short* __restrict__ qb, const unsigned short* __restrict__ kfrag,
        const unsigned short* __restrict__ vfrag, const int* __restrict__ mask,
        float* __restrict__ out, int b0){
    const int bid = blockIdx.x;
    int b, qt, bk_;
    if(gridDim.x == 256){ b = (bid&7)>>1; qt = (bid>>3)*2 + (bid&1); bk_ = b; }
    else                { b = b0; qt = bid; bk_ = 0; }
    const int tid = threadIdx.x, w4 = tid>>6, lane = tid&63, quad = lane>>4, lq = lane&15;
    const int qg = w4>>2, w = w4&3;
    const int qbase = qt*64 + 32*qg;

    __shared__ __align__(16) unsigned char smem[131072];

    // Q as B-operand frags (rows qbase+16rg+lq)
    s16x8 qf[2][8];
    #pragma unroll
    for(int rg=0; rg<2; rg++){
        size_t row = (size_t)(b*4096 + qbase + 16*rg + lq);
        #pragma unroll
        for(int ks=0; ks<8; ks++)
            qf[rg][ks] = *(const s16x8*)(qb + row*256 + ks*32 + quad*8);
    }

    f32x4 oacc[16][2];                 // O^T partial: h=16t+4quad+r, q=16rg+lq
    #pragma unroll
    for(int t=0;t<16;t++){ oacc[t][0] = (f32x4)(0.0f); oacc[t][1] = (f32x4)(0.0f); }
    float rsum[2] = {0.0f, 0.0f};

    const unsigned char* kfb = (const unsigned char*)(kfrag + (size_t)bk_*1048576);
    const unsigned char* vfb = (const unsigned char*)(vfrag + (size_t)bk_*1048576);
    const int* mp0 = mask + ((size_t)(b*4096 + qbase) + lq)*4096 + 16*w + 4*quad;
    const unsigned lsl = w4*1024 + lane*16;   // per-lane global offset within 8KB round
    const unsigned ldd = w4*1024;             // wave-uniform LDS offset

    // prologue: mask kt=0 into regs (nt), stage kt=0 into buf0
    i32x4 mA0 = ntload4(mp0);
    i32x4 mA1 = ntload4(mp0 + (size_t)16*4096);
    #pragma unroll
    for(int r=0; r<4; r++){
        glds16(kfb + r*8192 + lsl, smem + r*8192 + ldd);
        glds16(vfb + r*8192 + lsl, smem + 32768 + r*8192 + ldd);
    }
    i32x4 mN0 = mA0, mN1 = mA1;

    for(int kt=0; kt<64; kt++){
        const int cb = kt & 1;
        __syncthreads();   // drains staging + mask prefetch issued one body ago
        // ---- issue next-iteration memory FIRST (full body of latency slack) ----
        if(kt < 63){
            mN0 = ntload4(mp0 + (size_t)(kt+1)*64);
            mN1 = ntload4(mp0 + (size_t)16*4096 + (kt+1)*64);
            const unsigned char* gK = kfb + (size_t)(kt+1)*32768;
            const unsigned char* gV = vfb + (size_t)(kt+1)*32768;
            unsigned char* dst = smem + (cb^1)*65536;
            #pragma unroll
            for(int r=0; r<4; r++){
                glds16(gK + r*8192 + lsl, dst + r*8192 + ldd);
                glds16(gV + r*8192 + lsl, dst + 32768 + r*8192 + ldd);
            }
        }
        const unsigned short* bK = (const unsigned short*)(smem + cb*65536);
        const unsigned short* bV = (const unsigned short*)(smem + cb*65536 + 32768);

        // ---- S^T: D[n2local=4quad+r][q=lq] ----
        f32x4 sacc0 = (f32x4)(0.0f), sacc1 = (f32x4)(0.0f);
        #pragma unroll
        for(int ks=0; ks<8; ks++){
            s16x8 kf = *(const s16x8*)(bK + ((w*8 + ks)*64 + lane)*8);
            sacc0 = MFMA16(kf, qf[0][ks], sacc0);
            sacc1 = MFMA16(kf, qf[1][ks], sacc1);
        }
        // ---- mask + exp + pack (C rows 4quad+r == PV k=4quad+j) ----
        s16x4 pb0, pb1;
        {
            float p;
            p = (mA0.x>0)?__expf(sacc0[0]*0.0625f):1.0f; rsum[0]+=p; pb0[0]=(short)f2bf(p);
            p = (mA0.y>0)?__expf(sacc0[1]*0.0625f):1.0f; rsum[0]+=p; pb0[1]=(short)f2bf(p);
            p = (mA0.z>0)?__expf(sacc0[2]*0.0625f):1.0f; rsum[0]+=p; pb0[2]=(short)f2bf(p);
            p = (mA0.w>0)?__expf(sacc0[3]*0.0625f):1.0f; rsum[0]+=p; pb0[3]=(short)f2bf(p);
            p = (mA1.x>0)?__expf(sacc1[0]*0.0625f):1.0f; rsum[1]+=p; pb1[0]=(short)f2bf(p);
            p = (mA1.y>0)?__expf(sacc1[1]*0.0625f):1.0f; rsum[1]+=p; pb1[1]=(short)f2bf(p);
            p = (mA1.z>0)?__expf(sacc1[2]*0.0625f):1.0f; rsum[1]+=p; pb1[2]=(short)f2bf(p);
            p = (mA1.w>0)?__expf(sacc1[3]*0.0625f):1.0f; rsum[1]+=p; pb1[3]=(short)f2bf(p);
        }
        // ---- PV ----
        #pragma unroll
        for(int t2=0; t2<8; t2++){
            s16x8 vv = *(const s16x8*)(bV + ((w*8 + t2)*64 + lane)*8);
            s16x4 vlo = __builtin_shufflevector(vv, vv, 0,1,2,3);
            s16x4 vhi = __builtin_shufflevector(vv, vv, 4,5,6,7);
            oacc[2*t2  ][0] = mfma_pv(vlo, pb0, oacc[2*t2  ][0]);
            oacc[2*t2  ][1] = mfma_pv(vlo, pb1, oacc[2*t2  ][1]);
            oacc[2*t2+1][0] = mfma_pv(vhi, pb0, oacc[2*t2+1][0]);
            oacc[2*t2+1][1] = mfma_pv(vhi, pb1, oacc[2*t2+1][1]);
        }
        // rotate mask double-buffer
        mA0 = mN0; mA1 = mN1;
    }

    // ---- epilogue: alias buf0 region (safe: buf0 last read kt=62; all waves
    // past kt=63's barrier) ----
    float* sRS  = (float*)smem;              // [8][32]
    float* sRed = (float*)(smem + 1024);     // [4][2081]
    #pragma unroll
    for(int rg=0; rg<2; rg++){
        float v = rsum[rg];
        v += __shfl_xor(v, 16);
        v += __shfl_xor(v, 32);
        if(quad == 0) sRS[(qg*4 + w)*32 + 16*rg + lq] = v;
    }
    for(int g=0; g<2; g++){
        for(int c=0; c<4; c++){
            __syncthreads();
            if(qg == g){
                #pragma unroll
                for(int tt=0; tt<4; tt++){
                    int t = 4*c + tt;
                    #pragma unroll
                    for(int rg=0; rg<2; rg++){
                        #pragma unroll
                        for(int r=0; r<4; r++)
                            sRed[w*2081 + (16*rg+lq)*65 + 16*tt + 4*quad + r] = oacc[t][rg][r];
                    }
                }
            }
            __syncthreads();
            #pragma unroll
            for(int j=0; j<4; j++){
                int idx = j*512 + tid;
                int hl = idx & 63, q = idx >> 6;
                float s  = sRed[0*2081 + q*65+hl] + sRed[1*2081 + q*65+hl]
                         + sRed[2*2081 + q*65+hl] + sRed[3*2081 + q*65+hl];
                float rs = sRS[(g*4+0)*32+q] + sRS[(g*4+1)*32+q]
                         + sRS[(g*4+2)*32+q] + sRS[(g*4+3)*32+q];
                ntstoref(s / rs,
                    &out[((size_t)(b*4096 + qt*64 + 32*g + q))*256 + 64*c + hl]);
            }
        }
    }
}

extern "C" void kernel_launch(void* const* d_in, const int* in_sizes, int n_in,
                              void* d_out, int out_size, void* d_ws, size_t ws_size,
                              hipStream_t stream){
    (void)in_sizes; (void)n_in; (void)out_size;
    const float* x1 = (const float*)d_in[0];
    const float* x2 = (const float*)d_in[1];
    const int*   mk = (const int*)  d_in[2];
    const float* Wq = (const float*)d_in[3];
    const float* bq = (const float*)d_in[4];
    const float* Wk = (const float*)d_in[5];
    const float* bk = (const float*)d_in[6];
    const float* Wv = (const float*)d_in[7];
    const float* bv = (const float*)d_in[8];
    float* out = (float*)d_out;
    char* ws = (char*)d_ws;

    // ws layout: wt 384K @0 | q 8M | kfrag | vfrag
    unsigned short* wt = (unsigned short*)ws;
    unsigned short* qb = (unsigned short*)(ws + 393216);
    const size_t kvoff = 393216 + 8388608;

    wt_prep<<<dim3(32,3), 256, 0, stream>>>(Wq, Wk, Wv, wt);

    if(ws_size >= kvoff + 16ull*1024*1024){
        unsigned short* kf = (unsigned short*)(ws + kvoff);
        unsigned short* vf = (unsigned short*)(ws + kvoff + 8388608);
        proj_all<<<dim3(64,3,4), 256, 0, stream>>>(x1, x2, wt, bq, bk, bv, 0,
                                                   qb, kf, vf);
        attn<<<256, 512, 0, stream>>>(qb, kf, vf, mk, out, 0);
    } else {
        unsigned short* kf = (unsigned short*)(ws + kvoff);
        unsigned short* vf = (unsigned short*)(ws + kvoff + 2097152);
        for(int b=0;b<4;b++){
            proj_all<<<dim3(64,3,1), 256, 0, stream>>>(x1, x2, wt, bq, bk, bv, b,
                                                       qb, kf, vf);
            attn<<<64, 512, 0, stream>>>(qb, kf, vf, mk, out, b);
        }
    }
}